// Round 10
// baseline (467.337 us; speedup 1.0000x reference)
//
#include <hip/hip_runtime.h>
#include <cstddef>

#define B_   4
#define S_   8192
#define D_   512
#define H_   8
#define HD_  64
#define NROW (B_ * S_)              // 32768
#define NQ   ((size_t)NROW * D_)    // 16777216 elements per q/k/v buffer

typedef __attribute__((ext_vector_type(4))) float  f32x4;
typedef __attribute__((ext_vector_type(8))) short  s16x8;
typedef __attribute__((ext_vector_type(4))) unsigned short u16x4;
typedef __attribute__((ext_vector_type(8))) unsigned short u16x8;

__device__ __forceinline__ float phi_f(float x) {
    return x > 0.0f ? x + 1.0f : expf(x);   // elu(x)+1
}
__device__ __forceinline__ float bf2f(unsigned short u) {
    return __uint_as_float(((unsigned int)u) << 16);
}
__device__ __forceinline__ unsigned short f2bf(float f) {
    unsigned int u = __float_as_uint(f);
    u += 0x7fffu + ((u >> 16) & 1u);        // round-to-nearest-even
    return (unsigned short)(u >> 16);
}

#define GLOBAL_AS(p) ((const __attribute__((address_space(1))) void*)(p))
#define LDS_AS(p)    ((__attribute__((address_space(3))) void*)(p))

// ---------------------------------------------------------------------------
// Mask layout detector: 1 = byte-per-element (bool), 0 = 4-byte layout.
// (R11, verified)
// ---------------------------------------------------------------------------
__global__ void detect_mask(const unsigned char* __restrict__ m, int* __restrict__ flag) {
    __shared__ int sany;
    if (threadIdx.x == 0) sany = 0;
    __syncthreads();
    const uint4* mw = (const uint4*)m;      // 32768 B = 2048 uint4
    unsigned int any = 0;
    #pragma unroll
    for (int r = 0; r < 8; ++r) {
        const uint4 w = mw[r * 256 + threadIdx.x];
        any |= (w.x | w.y | w.z | w.w) & 0xFFFFFF00u;
    }
    if (any) atomicOr(&sany, 1);
    __syncthreads();
    if (threadIdx.x == 0) *flag = sany ? 1 : 0;
}

// ---------------------------------------------------------------------------
// Convert query/w_in/w_out -> bf16; mask -> float (1.0 keep / 0.0 ignore).
// ---------------------------------------------------------------------------
__global__ __launch_bounds__(256) void convert_all(
    const float* __restrict__ q,  unsigned short* __restrict__ qb,
    const float* __restrict__ wi, unsigned short* __restrict__ wib,
    const float* __restrict__ wo, unsigned short* __restrict__ wob,
    const unsigned char* __restrict__ kpm, const int* __restrict__ flag,
    float* __restrict__ fmask)
{
    const size_t i = (size_t)blockIdx.x * 256 + threadIdx.x;
    {   // query: 16777216 / 4 = 4194304 threads exactly
        const float4 v = *(const float4*)&q[i * 4];
        u16x4 o; o.x = f2bf(v.x); o.y = f2bf(v.y); o.z = f2bf(v.z); o.w = f2bf(v.w);
        *(u16x4*)&qb[i * 4] = o;
    }
    if (i < 786432 / 4) {
        const float4 v = *(const float4*)&wi[i * 4];
        u16x4 o; o.x = f2bf(v.x); o.y = f2bf(v.y); o.z = f2bf(v.z); o.w = f2bf(v.w);
        *(u16x4*)&wib[i * 4] = o;
    }
    if (i < 262144 / 4) {
        const float4 v = *(const float4*)&wo[i * 4];
        u16x4 o; o.x = f2bf(v.x); o.y = f2bf(v.y); o.z = f2bf(v.z); o.w = f2bf(v.w);
        *(u16x4*)&wob[i * 4] = o;
    }
    if (i < NROW) {
        const bool ignore = (*flag) ? (kpm[i] != 0) : (((const int*)kpm)[i] != 0);
        fmask[i] = ignore ? 0.0f : 1.0f;
    }
}

// ---------------------------------------------------------------------------
// R12 bf16 MFMA GEMM: C[m][n] = sum_k A[m][k]*B[n][k] + bias[n].
// BM=256 x BN=128 tile, BK=32, 256 thr = 4 waves.  Each wave owns 64 rows x
// ALL 128 cols: acc[4][8] f32x4, 32 MFMA per K-step vs 12 frag ds_reads.
// Rationale: R2/R7/R8/R10 all land at 98-113 µs across four different sync
// disciplines -> sync is not the limiter.  Counters (MfmaUtil 22, VALU 40,
// HBM 18, conflicts 0) say issue-overhead-bound; doubling MFMA per overhead
// op is the knob.  B-frags are identical across waves (same-address LDS
// reads broadcast - free).
// Sync skeleton = R7a verified depth-1 dbuf: stage(kt+1) then compute(kt)
// then __syncthreads (its vmcnt/lgkm drain IS the depth-1 wait).  No novel
// sync structure.
// T1 XCD swizzle (grids 1536 / 512 blocks, %8==0).  T2 swizzle via
// pre-swizzled global source (conflicts=0 verified R3).
// mode 0: in-proj epilogue -> phi / phi*mask / *mask into q/k/v bf16.
// mode 1: out-proj epilogue -> fp32 to Cout.
// ---------------------------------------------------------------------------
__global__ __launch_bounds__(256) void gemm_mfma(
    const unsigned short* __restrict__ A,  int lda,
    const unsigned short* __restrict__ Bw, int ldb,
    const float* __restrict__ bias, int K, int mode,
    const float* __restrict__ fmask,
    unsigned short* __restrict__ Cq,
    unsigned short* __restrict__ Ck,
    unsigned short* __restrict__ Cv,
    float* __restrict__ Cout)
{
    __shared__ __align__(16) unsigned short As[2][256 * 32];  // 32 KB
    __shared__ __align__(16) unsigned short Bs[2][128 * 32];  // 16 KB
    __shared__ float fm[256];

    const int t    = threadIdx.x;
    const int lane = t & 63;
    const int wave = t >> 6;            // 0..3, owns rows [wave*64, +64)

    // T1 XCD swizzle (bijective: nwg % 8 == 0 for both launches)
    const int nbx = gridDim.x;
    const int nwg = nbx * gridDim.y;
    int id = blockIdx.y * nbx + blockIdx.x;
    id = (id & 7) * (nwg >> 3) + (id >> 3);
    const int m0 = (id / nbx) * 256;
    const int n0 = (id % nbx) * 128;

    if (mode == 0) fm[t] = fmask[m0 + t];   // 256 rows, 256 threads

    f32x4 acc[4][8] = {};

    // staging: lane l -> row l>>2 within a 16-row group, physical chunk l&3
    // (linear LDS dest); source chunk pre-swizzled so LDS(r,c')=G(r,c'^((r>>1)&3))
    const int sr  = lane >> 2;
    const int skc = (((lane & 3) ^ ((lane >> 3) & 3))) * 8;

    const int nt = K >> 5;              // 16 K-steps

    #define STAGE(kt_, buf_)                                                            \
        do {                                                                            \
            const int k0_ = (kt_) << 5;                                                 \
            _Pragma("unroll")                                                           \
            for (int j = 0; j < 4; ++j) {   /* A: wave rows [wave*64, +64) */           \
                const int row = wave * 64 + j * 16;                                     \
                const unsigned short* g = A + (size_t)(m0 + row + sr) * lda + k0_ + skc;\
                __builtin_amdgcn_global_load_lds(GLOBAL_AS(g),                          \
                    LDS_AS(&As[(buf_)][row * 32]), 16, 0, 0);                           \
            }                                                                           \
            _Pragma("unroll")                                                           \
            for (int j = 0; j < 2; ++j) {   /* B: wave rows [wave*32, +32) */           \
                const int row = wave * 32 + j * 16;                                     \
                const unsigned short* g = Bw + (size_t)(n0 + row + sr) * ldb + k0_ + skc;\
                __builtin_amdgcn_global_load_lds(GLOBAL_AS(g),                          \
                    LDS_AS(&Bs[(buf_)][row * 32]), 16, 0, 0);                           \
            }                                                                           \
        } while (0)

    // prologue: stage tile 0, drain
    STAGE(0, 0);
    __syncthreads();

    // frag read addressing (swizzle-aware)
    const int fr = lane & 15;
    const int cn = lane >> 4;
    const int fo = (cn ^ ((fr >> 1) & 3)) * 8;

    for (int kt = 0; kt < nt; ++kt) {
        const int cur = kt & 1;
        if (kt + 1 < nt) STAGE(kt + 1, cur ^ 1);   // lands before end-of-iter drain

        s16x8 af[4], bf[8];
        #pragma unroll
        for (int i = 0; i < 4; ++i)
            af[i] = *(const s16x8*)&As[cur][(wave * 64 + i * 16 + fr) * 32 + fo];
        #pragma unroll
        for (int j = 0; j < 8; ++j)
            bf[j] = *(const s16x8*)&Bs[cur][(j * 16 + fr) * 32 + fo];
        #pragma unroll
        for (int i = 0; i < 4; ++i)
            #pragma unroll
            for (int j = 0; j < 8; ++j)
                acc[i][j] = __builtin_amdgcn_mfma_f32_16x16x32_bf16(af[i], bf[j], acc[i][j], 0, 0, 0);

        __syncthreads();    // drains stage(kt+1) loads + barrier (depth-1 wait)
    }
    #undef STAGE

    // Epilogue. C/D layout: col = lane&15, row = (lane>>4)*4 + reg.
    const int colf = lane & 15;
    const int rowq = (lane >> 4) * 4;
    float bj[8];
    #pragma unroll
    for (int j = 0; j < 8; ++j) bj[j] = bias[n0 + j * 16 + colf];

    if (mode == 1) {
        #pragma unroll
        for (int i = 0; i < 4; ++i)
            #pragma unroll
            for (int r = 0; r < 4; ++r) {
                const int m = m0 + wave * 64 + i * 16 + rowq + r;
                #pragma unroll
                for (int j = 0; j < 8; ++j) {
                    const int n = n0 + j * 16 + colf;
                    Cout[(size_t)m * D_ + n] = acc[i][j][r] + bj[j];
                }
            }
    } else {
        const int region = n0 >> 9;     // 0:q 1:k 2:v (BN=128 divides 512)
        unsigned short* Cb = region == 0 ? Cq : (region == 1 ? Ck : Cv);
        #pragma unroll
        for (int i = 0; i < 4; ++i)
            #pragma unroll
            for (int r = 0; r < 4; ++r) {
                const int ml = wave * 64 + i * 16 + rowq + r;
                const int m  = m0 + ml;
                const float mk = fm[ml];
                #pragma unroll
                for (int j = 0; j < 8; ++j) {
                    const int n  = (n0 & 511) + j * 16 + colf;
                    float v = acc[i][j][r] + bj[j];
                    if (region == 0)      v = phi_f(v);
                    else if (region == 1) v = phi_f(v) * mk;
                    else                  v = v * mk;
                    Cb[(size_t)m * D_ + n] = f2bf(v);
                }
            }
    }
}

// ---------------------------------------------------------------------------
// Partial kv = k^T v (64x64) and k_sum per (head, S-chunk, wave-group).
// (R11, verified: 8x8 tile, 4-wave s-split, padded LDS, T14 async prefetch)
// ---------------------------------------------------------------------------
__global__ __launch_bounds__(256) void kv_reduce(
    const unsigned short* __restrict__ kbuf,   // [NROW][512] bf16
    const unsigned short* __restrict__ vbuf,
    float* __restrict__ part_kv,               // [32*64][4096]
    float* __restrict__ part_ks)               // [32*64][64]
{
    const int bh = blockIdx.x, chunk = blockIdx.y;   // chunk 0..15
    const int b = bh >> 3, h = bh & 7;

    __shared__ __align__(16) float Ks[16][68];
    __shared__ __align__(16) float Vs[16][68];

    const int t    = threadIdx.x;
    const int wave = t >> 6;
    const int lane = t & 63;
    const int tx   = lane & 7;
    const int ty   = lane >> 3;

    const int sr = (t & 127) >> 3;
    const int sc = (t & 7) * 8;
    const unsigned short* src = (t < 128 ? kbuf : vbuf) + (size_t)b * S_ * D_ + h * HD_;
    float (*dst)[68] = (t < 128) ? Ks : Vs;

    float acc[8][8] = {};
    float ks[8] = {};
    const int s0 = chunk * (S_ / 16);
    const int NIT = 32;

    u16x8 x = *(const u16x8*)&src[(size_t)(s0 + sr) * D_ + sc];

    for (int it = 0; it < NIT; ++it) {
        __syncthreads();
        float4 f0, f1;
        f0.x = bf2f(x[0]); f0.y = bf2f(x[1]); f0.z = bf2f(x[2]); f0.w = bf2f(x[3]);
        f1.x = bf2f(x[4]); f1.y = bf2f(x[5]); f1.z = bf2f(x[6]); f1.w = bf2f(x[7]);
        *(float4*)&dst[sr][sc]     = f0;
        *(float4*)&dst[sr][sc + 4] = f1;
        __syncthreads();
        u16x8 xn = {};
        if (it + 1 < NIT)
            xn = *(const u16x8*)&src[(size_t)(s0 + (it + 1) * 16 + sr) * D_ + sc];
        #pragma unroll
        for (int ss0 = 0; ss0 < 4; ++ss0) {
            const int ss = wave + ss0 * 4;
            const float4 a0 = *(const float4*)&Ks[ss][ty * 8];
            const float4 a1 = *(const float4*)&Ks[ss][ty * 8 + 4];
            const float4 v0 = *(const float4*)&Vs[ss][tx * 8];
            const float4 v1 = *(const float4*)&Vs[ss][tx * 8 + 4];
            const float av[8] = {a0.x, a0.y, a0.z, a0.w, a1.x, a1.y, a1.z, a1.w};
            const float vv[8] = {v0.x, v0.y, v0.z, v0.w, v1.x, v1.y, v1.z, v1.w};
            #pragma unroll
            for (int i2 = 0; i2 < 8; ++i2)
                #pragma unroll
                for (int j2 = 0; j2 < 8; ++j2)
                    acc[i2][j2] += av[i2] * vv[j2];
            if (tx == 0) {
                #pragma unroll
                for (int i2 = 0; i2 < 8; ++i2) ks[i2] += av[i2];
            }
        }
        x = xn;
    }

    const int p = bh * 64 + chunk * 4 + wave;
    float* pk = part_kv + (size_t)p * 4096;
    #pragma unroll
    for (int i2 = 0; i2 < 8; ++i2) {
        #pragma unroll
        for (int j4 = 0; j4 < 2; ++j4) {
            float4 o;
            o.x = acc[i2][j4 * 4 + 0]; o.y = acc[i2][j4 * 4 + 1];
            o.z = acc[i2][j4 * 4 + 2]; o.w = acc[i2][j4 * 4 + 3];
            *(float4*)&pk[(ty * 8 + i2) * 64 + tx * 8 + j4 * 4] = o;
        }
    }
    if (tx == 0) {
        float* ps = part_ks + (size_t)p * 64;
        #pragma unroll
        for (int i2 = 0; i2 < 8; ++i2) ps[ty * 8 + i2] = ks[i2];
    }
}

// ---------------------------------------------------------------------------
// Sum 64 partials; emit kv TRANSPOSED in bf16 ([e][d]) and ksum bf16.
// ---------------------------------------------------------------------------
__global__ void kv_reduce2(const float* __restrict__ part_kv,
                           const float* __restrict__ part_ks,
                           unsigned short* __restrict__ kvT,    // [32][64][64]
                           unsigned short* __restrict__ ksumb)  // [32][64]
{
    const int i = blockIdx.x * 256 + threadIdx.x;   // 512 blocks -> 131072 exact
    if (i < 32 * 4096) {
        const int bh = i >> 12, de = i & 4095;
        const int d = de >> 6, e = de & 63;
        float s = 0.0f;
        #pragma unroll
        for (int c = 0; c < 64; ++c) s += part_kv[(size_t)(bh * 64 + c) * 4096 + de];
        kvT[bh * 4096 + e * 64 + d] = f2bf(s);
    }
    if (i < 32 * 64) {
        const int bh = i >> 6, e = i & 63;
        float s = 0.0f;
        #pragma unroll
        for (int c = 0; c < 64; ++c) s += part_ks[(size_t)(bh * 64 + c) * 64 + e];
        ksumb[i] = f2bf(s);
    }
}

// ---------------------------------------------------------------------------
// attn via MFMA, no LDS, no barriers.  (R5, verified)
// ---------------------------------------------------------------------------
__global__ __launch_bounds__(256) void apply_attn_mfma(
    const unsigned short* __restrict__ qphi,   // [NROW][512] bf16 (phi'd)
    const unsigned short* __restrict__ kvT,    // [32][64][64] bf16
    const unsigned short* __restrict__ ksumb,  // [32][64] bf16
    unsigned short* __restrict__ attnb)        // [NROW][512] bf16
{
    const int bh = blockIdx.x;
    const int b  = bh >> 3, h = bh & 7;
    const int m0 = blockIdx.y * 128;

    const int t    = threadIdx.x;
    const int lane = t & 63;
    const int wave = t >> 6;
    const int fr   = lane & 15;
    const int fk   = (lane >> 4) * 8;
    const int row0 = m0 + wave * 32;

    const unsigned short* Ah = qphi + (size_t)(b * S_ + row0) * D_ + h * HD_;
    const unsigned short* Bh = kvT + bh * 4096;
    const unsigned short* Kh = ksumb + bh * 64;

    s16x8 af[2][2], bfr[2][4], bd[2];
    #pragma unroll
    for (int kc = 0; kc < 2; ++kc) {
        #pragma unroll
        for (int i = 0; i < 2; ++i)
            af[kc][i] = *(const s16x8*)&Ah[(size_t)(i * 16 + fr) * D_ + kc * 32 + fk];
        #pragma unroll
        for (int j = 0; j < 4; ++j)
            bfr[kc][j] = *(const s16x8*)&Bh[(j * 16 + fr) * 64 + kc * 32 + fk];
        bd[kc] = *(const s16x8*)&Kh[kc * 32 + fk];
    }

    f32x4 acc[2][4] = {};
    f32x4 accd[2] = {};
    #pragma unroll
    for (int kc = 0; kc < 2; ++kc)
        #pragma unroll
        for (int i = 0; i < 2; ++i) {
            #pragma unroll
            for (int j = 0; j < 4; ++j)
                acc[i][j] = __builtin_amdgcn_mfma_f32_16x16x32_bf16(af[kc][i], bfr[kc][j], acc[i][j], 0, 0, 0);
            accd[i] = __builtin_amdgcn_mfma_f32_16x16x32_bf16(af[kc][i], bd[kc], accd[i], 0, 0, 0);
        }

    const int rq = (lane >> 4) * 4;
    #pragma unroll
    for (int i = 0; i < 2; ++i)
        #pragma unroll
        for (int r = 0; r < 4; ++r) {
            const float inv = 1.0f / fmaxf(accd[i][r], 1e-6f);
            const size_t row = (size_t)(b * S_ + row0 + i * 16 + rq + r);
            #pragma unroll
            for (int j = 0; j < 4; ++j)
                attnb[row * D_ + h * HD_ + j * 16 + fr] = f2bf(acc[i][j][r] * inv);
        }
}

// ---------------------------------------------------------------------------
extern "C" void kernel_launch(void* const* d_in, const int* in_sizes, int n_in,
                              void* d_out, int out_size, void* d_ws, size_t ws_size,
                              hipStream_t stream)
{
    const float* query       = (const float*)d_in[0];
    const unsigned char* kpm = (const unsigned char*)d_in[3];
    const float* w_in        = (const float*)d_in[4];
    const float* b_in        = (const float*)d_in[5];
    const float* w_out       = (const float*)d_in[6];
    const float* b_out       = (const float*)d_in[7];
    float* out = (float*)d_out;

    // workspace layout (attn aliases qb, which is dead after in-proj)
    unsigned short* qb    = (unsigned short*)d_ws;          // query bf16 / attn bf16
    unsigned short* qphi  = qb    + NQ;
    unsigned short* kpb   = qphi  + NQ;
    unsigned short* vmb   = kpb   + NQ;
    unsigned short* wib   = vmb   + NQ;
    unsigned short* wob   = wib   + 1536 * 512;
    float* fmask   = (float*)(wob + 512 * 512);
    float* part_kv = fmask + NROW;
    float* part_ks = part_kv + (size_t)2048 * 4096;
    unsigned short* kvTb  = (unsigned short*)(part_ks + 2048 * 64);
    unsigned short* ksumb = kvTb + 32 * 4096;
    int*   flag    = (int*)(ksumb + 32 * 64);

    hipLaunchKernelGGL(detect_mask, dim3(1), dim3(256), 0, stream, kpm, flag);
    hipLaunchKernelGGL(convert_all, dim3(16384), dim3(256), 0, stream,
                       query, qb, w_in, wib, w_out, wob, kpm, flag, fmask);

    // in-proj: M=32768, N=1536, K=512 -> grid (12, 128) = 1536 blocks
    hipLaunchKernelGGL(gemm_mfma, dim3(1536 / 128, NROW / 256), dim3(256), 0, stream,
                       qb, D_, wib, D_, b_in, D_, 0, fmask,
                       qphi, kpb, vmb, (float*)nullptr);

    hipLaunchKernelGGL(kv_reduce, dim3(32, 16), dim3(256), 0, stream, kpb, vmb, part_kv, part_ks);
    hipLaunchKernelGGL(kv_reduce2, dim3(512), dim3(256), 0, stream,
                       part_kv, part_ks, kvTb, ksumb);

    // attn: MFMA, writes into qb (dead after in-proj)
    hipLaunchKernelGGL(apply_attn_mfma, dim3(32, S_ / 128), dim3(256), 0, stream,
                       qphi, kvTb, ksumb, qb);

    // out-proj: M=32768, N=512, K=512 -> grid (4, 128) = 512 blocks
    hipLaunchKernelGGL(gemm_mfma, dim3(512 / 128, NROW / 256), dim3(256), 0, stream,
                       qb, D_, wob, D_, b_out, D_, 1, (const float*)nullptr,
                       (unsigned short*)nullptr, (unsigned short*)nullptr,
                       (unsigned short*)nullptr, out);
}

// Round 12
// 385.706 us; speedup vs baseline: 1.2116x; 1.2116x over previous
//
#include <hip/hip_runtime.h>
#include <cstddef>

#define B_   4
#define S_   8192
#define D_   512
#define H_   8
#define HD_  64
#define NROW (B_ * S_)              // 32768
#define NQ   ((size_t)NROW * D_)    // 16777216 elements per q/k/v buffer

typedef __attribute__((ext_vector_type(4))) float  f32x4;
typedef __attribute__((ext_vector_type(8))) short  s16x8;
typedef __attribute__((ext_vector_type(4))) unsigned short u16x4;
typedef __attribute__((ext_vector_type(8))) unsigned short u16x8;

__device__ __forceinline__ float phi_f(float x) {
    return x > 0.0f ? x + 1.0f : expf(x);   // elu(x)+1
}
__device__ __forceinline__ float bf2f(unsigned short u) {
    return __uint_as_float(((unsigned int)u) << 16);
}
__device__ __forceinline__ unsigned short f2bf(float f) {
    unsigned int u = __float_as_uint(f);
    u += 0x7fffu + ((u >> 16) & 1u);        // round-to-nearest-even
    return (unsigned short)(u >> 16);
}

#define GLOBAL_AS(p) ((const __attribute__((address_space(1))) void*)(p))
#define LDS_AS(p)    ((__attribute__((address_space(3))) void*)(p))

// ---------------------------------------------------------------------------
// Mask layout detector: 1 = byte-per-element (bool), 0 = 4-byte layout.
// R13 LESSON: the host-side in_sizes[3] shortcut picked the WRONG layout
// (absmax 1.07e-2) — in_sizes semantics are not what was assumed.  The
// data-derived device detector is load-bearing; always run it.  (~2 µs.)
// ---------------------------------------------------------------------------
__global__ void detect_mask(const unsigned char* __restrict__ m, int* __restrict__ flag) {
    __shared__ int sany;
    if (threadIdx.x == 0) sany = 0;
    __syncthreads();
    const uint4* mw = (const uint4*)m;      // 32768 B = 2048 uint4
    unsigned int any = 0;
    #pragma unroll
    for (int r = 0; r < 8; ++r) {
        const uint4 w = mw[r * 256 + threadIdx.x];
        any |= (w.x | w.y | w.z | w.w) & 0xFFFFFF00u;
    }
    if (any) atomicOr(&sany, 1);
    __syncthreads();
    if (threadIdx.x == 0) *flag = sany ? 1 : 0;
}

// ---------------------------------------------------------------------------
// Convert query/w_in/w_out -> bf16; mask -> float (1.0 keep / 0.0 ignore).
// ---------------------------------------------------------------------------
__global__ __launch_bounds__(256) void convert_all(
    const float* __restrict__ q,  unsigned short* __restrict__ qb,
    const float* __restrict__ wi, unsigned short* __restrict__ wib,
    const float* __restrict__ wo, unsigned short* __restrict__ wob,
    const unsigned char* __restrict__ kpm, const int* __restrict__ flag,
    float* __restrict__ fmask)
{
    const size_t i = (size_t)blockIdx.x * 256 + threadIdx.x;
    {   // query: 16777216 / 4 = 4194304 threads exactly
        const float4 v = *(const float4*)&q[i * 4];
        u16x4 o; o.x = f2bf(v.x); o.y = f2bf(v.y); o.z = f2bf(v.z); o.w = f2bf(v.w);
        *(u16x4*)&qb[i * 4] = o;
    }
    if (i < 786432 / 4) {
        const float4 v = *(const float4*)&wi[i * 4];
        u16x4 o; o.x = f2bf(v.x); o.y = f2bf(v.y); o.z = f2bf(v.z); o.w = f2bf(v.w);
        *(u16x4*)&wib[i * 4] = o;
    }
    if (i < 262144 / 4) {
        const float4 v = *(const float4*)&wo[i * 4];
        u16x4 o; o.x = f2bf(v.x); o.y = f2bf(v.y); o.z = f2bf(v.z); o.w = f2bf(v.w);
        *(u16x4*)&wob[i * 4] = o;
    }
    if (i < NROW) {
        const bool ignore = (*flag) ? (kpm[i] != 0) : (((const int*)kpm)[i] != 0);
        fmask[i] = ignore ? 0.0f : 1.0f;
    }
}

// ---------------------------------------------------------------------------
// bf16 MFMA GEMM (R8, verified): C[m][n] = sum_k A[m][k]*B[n][k] + bias[n].
// 128x128 tile, BK=32, 256 thr = 2x2 waves, 4x4 frags of 16x16x32_bf16.
// T1 XCD swizzle; T2 swizzle via pre-swizzled global source (conflicts = 0,
// verified R3); depth-2 pipeline, 3 LDS buffers, counted vmcnt(4) + raw
// s_barrier (verified R4: passed, stable; ~98-100 µs in-proj).
// Boxed-in evidence: sync variants (R7/R8/R10) all ~equal; BM=256 tile-up
// (R12) hit the >128-VGPR occupancy cliff (140 regs -> 10.7% occ -> 170 µs).
// ~100 µs is this shape's ceiling for this structure; K=512 too short for
// the deep-pipeline schedules (R9/R10 measured).
// mode 0: in-proj epilogue -> phi / phi*mask / *mask into q/k/v bf16 buffers.
// mode 1: out-proj epilogue -> fp32 to Cout.
// ---------------------------------------------------------------------------
__global__ __launch_bounds__(256) void gemm_mfma(
    const unsigned short* __restrict__ A,  int lda,
    const unsigned short* __restrict__ Bw, int ldb,
    const float* __restrict__ bias, int K, int mode,
    const float* __restrict__ fmask,
    unsigned short* __restrict__ Cq,
    unsigned short* __restrict__ Ck,
    unsigned short* __restrict__ Cv,
    float* __restrict__ Cout)
{
    __shared__ __align__(16) unsigned short As[3][128 * 32];  // [buf][m][k], 64B rows
    __shared__ __align__(16) unsigned short Bs[3][128 * 32];  // [buf][n][k]
    __shared__ float fm[128];

    const int t    = threadIdx.x;
    const int lane = t & 63;
    const int wave = t >> 6;            // 0..3
    const int wm   = wave & 1;          // wave m-offset (x64)
    const int wn   = wave >> 1;         // wave n-offset (x64)

    // T1 XCD swizzle (bijective: nwg % 8 == 0 for both launches)
    const int nbx = gridDim.x;
    const int nwg = nbx * gridDim.y;
    int id = blockIdx.y * nbx + blockIdx.x;
    id = (id & 7) * (nwg >> 3) + (id >> 3);
    const int m0 = (id / nbx) * 128;
    const int n0 = (id % nbx) * 128;

    if (mode == 0 && t < 128) fm[t] = fmask[m0 + t];

    f32x4 acc[4][4] = {};

    // staging: lane l -> LDS row l>>2, physical chunk l&3 (linear dest);
    // source chunk pre-swizzled so LDS(r,c') = global(r, c' ^ ((r>>1)&3))
    const int sr  = lane >> 2;                              // row-in-16
    const int skc = (((lane & 3) ^ ((lane >> 3) & 3))) * 8; // swizzled src chunk (elems)

    const int nt = K >> 5;              // K-steps of 32 (16 here)

    #define STAGE(kt_, buf_)                                                            \
        do {                                                                            \
            const int k0_ = (kt_) << 5;                                                 \
            _Pragma("unroll")                                                           \
            for (int j = 0; j < 2; ++j) {                                               \
                const int row = wave * 32 + j * 16;                                     \
                const unsigned short* g = A + (size_t)(m0 + row + sr) * lda + k0_ + skc;\
                __builtin_amdgcn_global_load_lds(GLOBAL_AS(g),                          \
                    LDS_AS(&As[(buf_)][row * 32]), 16, 0, 0);                           \
            }                                                                           \
            _Pragma("unroll")                                                           \
            for (int j = 0; j < 2; ++j) {                                               \
                const int row = wave * 32 + j * 16;                                     \
                const unsigned short* g = Bw + (size_t)(n0 + row + sr) * ldb + k0_ + skc;\
                __builtin_amdgcn_global_load_lds(GLOBAL_AS(g),                          \
                    LDS_AS(&Bs[(buf_)][row * 32]), 16, 0, 0);                           \
            }                                                                           \
        } while (0)

    // prologue: stage tiles 0 and 1 (no drain, no barrier yet)
    STAGE(0, 0);
    STAGE(1, 1);

    // frag read addressing (swizzle-aware)
    const int fr = lane & 15;           // m (or n) within 16
    const int cn = lane >> 4;           // logical 16B chunk 0..3
    const int fo = (cn ^ ((fr >> 1) & 3)) * 8;  // physical chunk -> element offset

    int cur = 0;                        // kt % 3
    for (int kt = 0; kt < nt; ++kt) {
        if (kt + 1 < nt) asm volatile("s_waitcnt vmcnt(4)" ::: "memory");
        else             asm volatile("s_waitcnt vmcnt(0)" ::: "memory");
        __builtin_amdgcn_s_barrier();   // raw barrier: no compiler vmcnt(0) drain

        if (kt + 2 < nt) {
            int nb = cur + 2; if (nb >= 3) nb -= 3;
            STAGE(kt + 2, nb);
        }

        s16x8 af[4], bf[4];
        #pragma unroll
        for (int i = 0; i < 4; ++i)
            af[i] = *(const s16x8*)&As[cur][(wm * 64 + i * 16 + fr) * 32 + fo];
        #pragma unroll
        for (int j = 0; j < 4; ++j)
            bf[j] = *(const s16x8*)&Bs[cur][(wn * 64 + j * 16 + fr) * 32 + fo];
        #pragma unroll
        for (int i = 0; i < 4; ++i)
            #pragma unroll
            for (int j = 0; j < 4; ++j)
                acc[i][j] = __builtin_amdgcn_mfma_f32_16x16x32_bf16(af[i], bf[j], acc[i][j], 0, 0, 0);

        if (++cur == 3) cur = 0;
    }
    #undef STAGE

    // Epilogue. C/D layout: n = lane&15, m = (lane>>4)*4 + reg.
    const int col  = lane & 15;
    const int rowq = (lane >> 4) * 4;
    float bj[4];
    #pragma unroll
    for (int j = 0; j < 4; ++j) bj[j] = bias[n0 + wn * 64 + j * 16 + col];

    if (mode == 1) {
        #pragma unroll
        for (int i = 0; i < 4; ++i)
            #pragma unroll
            for (int r = 0; r < 4; ++r) {
                const int m = m0 + wm * 64 + i * 16 + rowq + r;
                #pragma unroll
                for (int j = 0; j < 4; ++j) {
                    const int n = n0 + wn * 64 + j * 16 + col;
                    Cout[(size_t)m * D_ + n] = acc[i][j][r] + bj[j];
                }
            }
    } else {
        const int region = n0 >> 9;     // 0:q 1:k 2:v (BN=128 divides 512)
        unsigned short* Cb = region == 0 ? Cq : (region == 1 ? Ck : Cv);
        #pragma unroll
        for (int i = 0; i < 4; ++i)
            #pragma unroll
            for (int r = 0; r < 4; ++r) {
                const int ml = wm * 64 + i * 16 + rowq + r;
                const int m  = m0 + ml;
                const float mk = fm[ml];
                #pragma unroll
                for (int j = 0; j < 4; ++j) {
                    const int n  = (n0 & 511) + wn * 64 + j * 16 + col;
                    float v = acc[i][j][r] + bj[j];
                    if (region == 0)      v = phi_f(v);
                    else if (region == 1) v = phi_f(v) * mk;
                    else                  v = v * mk;
                    Cb[(size_t)m * D_ + n] = f2bf(v);
                }
            }
    }
}

// ---------------------------------------------------------------------------
// Partial kv = k^T v (64x64) and k_sum per (head, S-chunk, wave-group).
// (R11, verified: 8x8 tile, 4-wave s-split, padded LDS, T14 async prefetch)
// ---------------------------------------------------------------------------
__global__ __launch_bounds__(256) void kv_reduce(
    const unsigned short* __restrict__ kbuf,   // [NROW][512] bf16
    const unsigned short* __restrict__ vbuf,
    float* __restrict__ part_kv,               // [32*64][4096]
    float* __restrict__ part_ks)               // [32*64][64]
{
    const int bh = blockIdx.x, chunk = blockIdx.y;   // chunk 0..15
    const int b = bh >> 3, h = bh & 7;

    __shared__ __align__(16) float Ks[16][68];
    __shared__ __align__(16) float Vs[16][68];

    const int t    = threadIdx.x;
    const int wave = t >> 6;
    const int lane = t & 63;
    const int tx   = lane & 7;
    const int ty   = lane >> 3;

    const int sr = (t & 127) >> 3;
    const int sc = (t & 7) * 8;
    const unsigned short* src = (t < 128 ? kbuf : vbuf) + (size_t)b * S_ * D_ + h * HD_;
    float (*dst)[68] = (t < 128) ? Ks : Vs;

    float acc[8][8] = {};
    float ks[8] = {};
    const int s0 = chunk * (S_ / 16);
    const int NIT = 32;

    u16x8 x = *(const u16x8*)&src[(size_t)(s0 + sr) * D_ + sc];

    for (int it = 0; it < NIT; ++it) {
        __syncthreads();
        float4 f0, f1;
        f0.x = bf2f(x[0]); f0.y = bf2f(x[1]); f0.z = bf2f(x[2]); f0.w = bf2f(x[3]);
        f1.x = bf2f(x[4]); f1.y = bf2f(x[5]); f1.z = bf2f(x[6]); f1.w = bf2f(x[7]);
        *(float4*)&dst[sr][sc]     = f0;
        *(float4*)&dst[sr][sc + 4] = f1;
        __syncthreads();
        u16x8 xn = {};
        if (it + 1 < NIT)
            xn = *(const u16x8*)&src[(size_t)(s0 + (it + 1) * 16 + sr) * D_ + sc];
        #pragma unroll
        for (int ss0 = 0; ss0 < 4; ++ss0) {
            const int ss = wave + ss0 * 4;
            const float4 a0 = *(const float4*)&Ks[ss][ty * 8];
            const float4 a1 = *(const float4*)&Ks[ss][ty * 8 + 4];
            const float4 v0 = *(const float4*)&Vs[ss][tx * 8];
            const float4 v1 = *(const float4*)&Vs[ss][tx * 8 + 4];
            const float av[8] = {a0.x, a0.y, a0.z, a0.w, a1.x, a1.y, a1.z, a1.w};
            const float vv[8] = {v0.x, v0.y, v0.z, v0.w, v1.x, v1.y, v1.z, v1.w};
            #pragma unroll
            for (int i2 = 0; i2 < 8; ++i2)
                #pragma unroll
                for (int j2 = 0; j2 < 8; ++j2)
                    acc[i2][j2] += av[i2] * vv[j2];
            if (tx == 0) {
                #pragma unroll
                for (int i2 = 0; i2 < 8; ++i2) ks[i2] += av[i2];
            }
        }
        x = xn;
    }

    const int p = bh * 64 + chunk * 4 + wave;
    float* pk = part_kv + (size_t)p * 4096;
    #pragma unroll
    for (int i2 = 0; i2 < 8; ++i2) {
        #pragma unroll
        for (int j4 = 0; j4 < 2; ++j4) {
            float4 o;
            o.x = acc[i2][j4 * 4 + 0]; o.y = acc[i2][j4 * 4 + 1];
            o.z = acc[i2][j4 * 4 + 2]; o.w = acc[i2][j4 * 4 + 3];
            *(float4*)&pk[(ty * 8 + i2) * 64 + tx * 8 + j4 * 4] = o;
        }
    }
    if (tx == 0) {
        float* ps = part_ks + (size_t)p * 64;
        #pragma unroll
        for (int i2 = 0; i2 < 8; ++i2) ps[ty * 8 + i2] = ks[i2];
    }
}

// ---------------------------------------------------------------------------
// Sum 64 partials; emit kv TRANSPOSED in bf16 ([e][d]) and ksum bf16.
// ---------------------------------------------------------------------------
__global__ void kv_reduce2(const float* __restrict__ part_kv,
                           const float* __restrict__ part_ks,
                           unsigned short* __restrict__ kvT,    // [32][64][64]
                           unsigned short* __restrict__ ksumb)  // [32][64]
{
    const int i = blockIdx.x * 256 + threadIdx.x;   // 512 blocks -> 131072 exact
    if (i < 32 * 4096) {
        const int bh = i >> 12, de = i & 4095;
        const int d = de >> 6, e = de & 63;
        float s = 0.0f;
        #pragma unroll
        for (int c = 0; c < 64; ++c) s += part_kv[(size_t)(bh * 64 + c) * 4096 + de];
        kvT[bh * 4096 + e * 64 + d] = f2bf(s);
    }
    if (i < 32 * 64) {
        const int bh = i >> 6, e = i & 63;
        float s = 0.0f;
        #pragma unroll
        for (int c = 0; c < 64; ++c) s += part_ks[(size_t)(bh * 64 + c) * 64 + e];
        ksumb[i] = f2bf(s);
    }
}

// ---------------------------------------------------------------------------
// attn via MFMA, no LDS, no barriers.  (R5, verified)
// ---------------------------------------------------------------------------
__global__ __launch_bounds__(256) void apply_attn_mfma(
    const unsigned short* __restrict__ qphi,   // [NROW][512] bf16 (phi'd)
    const unsigned short* __restrict__ kvT,    // [32][64][64] bf16
    const unsigned short* __restrict__ ksumb,  // [32][64] bf16
    unsigned short* __restrict__ attnb)        // [NROW][512] bf16
{
    const int bh = blockIdx.x;
    const int b  = bh >> 3, h = bh & 7;
    const int m0 = blockIdx.y * 128;

    const int t    = threadIdx.x;
    const int lane = t & 63;
    const int wave = t >> 6;
    const int fr   = lane & 15;
    const int fk   = (lane >> 4) * 8;
    const int row0 = m0 + wave * 32;

    const unsigned short* Ah = qphi + (size_t)(b * S_ + row0) * D_ + h * HD_;
    const unsigned short* Bh = kvT + bh * 4096;
    const unsigned short* Kh = ksumb + bh * 64;

    s16x8 af[2][2], bfr[2][4], bd[2];
    #pragma unroll
    for (int kc = 0; kc < 2; ++kc) {
        #pragma unroll
        for (int i = 0; i < 2; ++i)
            af[kc][i] = *(const s16x8*)&Ah[(size_t)(i * 16 + fr) * D_ + kc * 32 + fk];
        #pragma unroll
        for (int j = 0; j < 4; ++j)
            bfr[kc][j] = *(const s16x8*)&Bh[(j * 16 + fr) * 64 + kc * 32 + fk];
        bd[kc] = *(const s16x8*)&Kh[kc * 32 + fk];
    }

    f32x4 acc[2][4] = {};
    f32x4 accd[2] = {};
    #pragma unroll
    for (int kc = 0; kc < 2; ++kc)
        #pragma unroll
        for (int i = 0; i < 2; ++i) {
            #pragma unroll
            for (int j = 0; j < 4; ++j)
                acc[i][j] = __builtin_amdgcn_mfma_f32_16x16x32_bf16(af[kc][i], bfr[kc][j], acc[i][j], 0, 0, 0);
            accd[i] = __builtin_amdgcn_mfma_f32_16x16x32_bf16(af[kc][i], bd[kc], accd[i], 0, 0, 0);
        }

    const int rq = (lane >> 4) * 4;
    #pragma unroll
    for (int i = 0; i < 2; ++i)
        #pragma unroll
        for (int r = 0; r < 4; ++r) {
            const float inv = 1.0f / fmaxf(accd[i][r], 1e-6f);
            const size_t row = (size_t)(b * S_ + row0 + i * 16 + rq + r);
            #pragma unroll
            for (int j = 0; j < 4; ++j)
                attnb[row * D_ + h * HD_ + j * 16 + fr] = f2bf(acc[i][j][r] * inv);
        }
}

// ---------------------------------------------------------------------------
extern "C" void kernel_launch(void* const* d_in, const int* in_sizes, int n_in,
                              void* d_out, int out_size, void* d_ws, size_t ws_size,
                              hipStream_t stream)
{
    const float* query       = (const float*)d_in[0];
    const unsigned char* kpm = (const unsigned char*)d_in[3];
    const float* w_in        = (const float*)d_in[4];
    const float* b_in        = (const float*)d_in[5];
    const float* w_out       = (const float*)d_in[6];
    const float* b_out       = (const float*)d_in[7];
    float* out = (float*)d_out;

    // workspace layout (attn aliases qb, which is dead after in-proj)
    unsigned short* qb    = (unsigned short*)d_ws;          // query bf16 / attn bf16
    unsigned short* qphi  = qb    + NQ;
    unsigned short* kpb   = qphi  + NQ;
    unsigned short* vmb   = kpb   + NQ;
    unsigned short* wib   = vmb   + NQ;
    unsigned short* wob   = wib   + 1536 * 512;
    float* fmask   = (float*)(wob + 512 * 512);
    float* part_kv = fmask + NROW;
    float* part_ks = part_kv + (size_t)2048 * 4096;
    unsigned short* kvTb  = (unsigned short*)(part_ks + 2048 * 64);
    unsigned short* ksumb = kvTb + 32 * 4096;
    int*   flag    = (int*)(ksumb + 32 * 64);

    hipLaunchKernelGGL(detect_mask, dim3(1), dim3(256), 0, stream, kpm, flag);
    hipLaunchKernelGGL(convert_all, dim3(16384), dim3(256), 0, stream,
                       query, qb, w_in, wib, w_out, wob, kpm, flag, fmask);

    // in-proj: M=32768, N=1536, K=512; epilogue -> qphi/kpb/vmb (bf16)
    hipLaunchKernelGGL(gemm_mfma, dim3(1536 / 128, NROW / 128), dim3(256), 0, stream,
                       qb, D_, wib, D_, b_in, D_, 0, fmask,
                       qphi, kpb, vmb, (float*)nullptr);

    hipLaunchKernelGGL(kv_reduce, dim3(32, 16), dim3(256), 0, stream, kpb, vmb, part_kv, part_ks);
    hipLaunchKernelGGL(kv_reduce2, dim3(512), dim3(256), 0, stream,
                       part_kv, part_ks, kvTb, ksumb);

    // attn: MFMA, writes into qb (dead after in-proj)
    hipLaunchKernelGGL(apply_attn_mfma, dim3(32, S_ / 128), dim3(256), 0, stream,
                       qphi, kvTb, ksumb, qb);

    // out-proj: M=32768, N=512, K=512 -> fp32 d_out
    hipLaunchKernelGGL(gemm_mfma, dim3(512 / 128, NROW / 128), dim3(256), 0, stream,
                       qb, D_, wob, D_, b_out, D_, 1, (const float*)nullptr,
                       (unsigned short*)nullptr, (unsigned short*)nullptr,
                       (unsigned short*)nullptr, out);
}